// Round 2
// 191.395 us; speedup vs baseline: 1.0063x; 1.0063x over previous
//
#include <hip/hip_runtime.h>

// Problem constants (from reference setup_inputs)
#define BB   64
#define SS   512
#define AA   8
#define DD   128
#define CC   1024
#define NCAND (BB * CC)   // 65536

// Output layout (flat fp32, tuple concatenated in return order)
#define OFF_REPR  0ULL
#define SZ_REPR   ((size_t)BB * CC * DD)        // 8388608
#define OFF_LABEL (OFF_REPR + SZ_REPR)          // 8388608
#define OFF_NUM   (OFF_LABEL + (size_t)BB * CC) // 8454144
#define OFF_LEN   (OFF_NUM + 1ULL)              // 8454145
#define OFF_MASK  (OFF_LEN + (size_t)BB)        // 8454209
#define OFF_LOC   (OFF_MASK + (size_t)BB * CC)  // 8519745

// Native vector type — __builtin_nontemporal_store rejects HIP_vector_type.
typedef float f32x4 __attribute__((ext_vector_type(4)));

// Fused kernel: 8192 blocks x 256 threads.
//  - Every block: 8 candidates, 32 lanes each -> float4 gather+mask+store
//    (512B coalesced segments), non-temporal (write-once, never re-read;
//    keeps L3 free for the 134MB word_repr gather working set).
//  - Side outputs (label/mask/loc) staged in LDS, then written as 3
//    coalesced segments by warp 0 (was: 32 scattered 4B stores/block).
//  - Blocks [0,64): additionally compute candidate_len for batch==blockIdx
//    (redundant re-read of idx/loc for 1024 candidates: ~20KB/block, noise).
//  - Block 0 thread 0 writes batch_candidate_num.
__global__ __launch_bounds__(256) void fused_kernel(
    const float* __restrict__ word_repr,
    const int*   __restrict__ anchor_cls,
    const int*   __restrict__ anchor_loc,
    const int*   __restrict__ cand_idx,
    const int*   __restrict__ cnum,
    float*       __restrict__ out)
{
    const int tid  = threadIdx.x;
    const int lane = tid & 31;
    const int g    = tid >> 5;                  // candidate group within block
    const int i0   = blockIdx.x * 8;
    const int i    = i0 + g;                    // candidate id, < 65536

    // side[0:8)=label, side[8:16)=mask, side[16:32)=loc (x,y interleaved)
    __shared__ float side[32];

    // Broadcast loads (uniform across the 32-lane group).
    const int b = cand_idx[3 * i + 0];
    const int w = cand_idx[3 * i + 1];
    const int a = cand_idx[3 * i + 2];
    const int base = (b * SS + w) * AA + a;      // row index into (B,S,A)

    const int2 loc = ((const int2*)anchor_loc)[base];
    const float m = (loc.x != loc.y) ? 1.0f : 0.0f;

    const f32x4 v = ((const f32x4*)word_repr)[(size_t)base * 32 + lane];
    f32x4 r = v * m;
    __builtin_nontemporal_store(
        r, ((f32x4*)(out + OFF_REPR)) + (size_t)i * 32 + lane);

    if (lane == 0) {
        side[g]          = (float)anchor_cls[base];
        side[8 + g]      = m;
        side[16 + 2 * g] = (float)loc.x;
        side[17 + 2 * g] = (float)loc.y;
    }
    __syncthreads();

    // Warp 0 drains side outputs as coalesced segments.
    if (tid < 8) {
        __builtin_nontemporal_store(side[tid], out + OFF_LABEL + i0 + tid);
    } else if (tid < 16) {
        __builtin_nontemporal_store(side[tid], out + OFF_MASK + i0 + (tid - 8));
    } else if (tid < 32) {
        __builtin_nontemporal_store(side[tid],
                                    out + OFF_LOC + 2 * (size_t)i0 + (tid - 16));
    }

    // candidate_len: first 64 blocks each reduce one batch's 1024 masks.
    if (blockIdx.x < BB) {
        const int bb = blockIdx.x;
        float msum = 0.0f;
#pragma unroll
        for (int j = 0; j < CC / 256; ++j) {
            const int c  = tid + j * 256;
            const int i2 = bb * CC + c;
            const int b2 = cand_idx[3 * i2 + 0];
            const int w2 = cand_idx[3 * i2 + 1];
            const int a2 = cand_idx[3 * i2 + 2];
            const int2 l2 = ((const int2*)anchor_loc)[(b2 * SS + w2) * AA + a2];
            msum += (l2.x != l2.y) ? 1.0f : 0.0f;
        }
#pragma unroll
        for (int off = 32; off > 0; off >>= 1)
            msum += __shfl_down(msum, off, 64);

        __shared__ float sm[4];
        if ((tid & 63) == 0) sm[tid >> 6] = msum;
        __syncthreads();
        if (tid == 0) {
            const float s = sm[0] + sm[1] + sm[2] + sm[3];
            out[OFF_LEN + bb] = fmaxf(s, 1.0f);
            if (bb == 0) out[OFF_NUM] = (float)(*cnum);
        }
    }
}

extern "C" void kernel_launch(void* const* d_in, const int* in_sizes, int n_in,
                              void* d_out, int out_size, void* d_ws, size_t ws_size,
                              hipStream_t stream) {
    const float* word_repr  = (const float*)d_in[0];
    const int*   anchor_cls = (const int*)  d_in[1];
    const int*   anchor_loc = (const int*)  d_in[2];
    const int*   cand_idx   = (const int*)  d_in[3];
    const int*   cnum       = (const int*)  d_in[4];
    float*       out        = (float*)      d_out;

    fused_kernel<<<dim3(NCAND / 8), dim3(256), 0, stream>>>(
        word_repr, anchor_cls, anchor_loc, cand_idx, cnum, out);
}

// Round 3
// 190.896 us; speedup vs baseline: 1.0089x; 1.0026x over previous
//
#include <hip/hip_runtime.h>

// Problem constants (from reference setup_inputs)
#define BB   64
#define SS   512
#define AA   8
#define DD   128
#define CC   1024
#define NCAND (BB * CC)   // 65536

// Output layout (flat fp32, tuple concatenated in return order)
#define OFF_REPR  0ULL
#define SZ_REPR   ((size_t)BB * CC * DD)        // 8388608
#define OFF_LABEL (OFF_REPR + SZ_REPR)          // 8388608
#define OFF_NUM   (OFF_LABEL + (size_t)BB * CC) // 8454144
#define OFF_LEN   (OFF_NUM + 1ULL)              // 8454145
#define OFF_MASK  (OFF_LEN + (size_t)BB)        // 8454209
#define OFF_LOC   (OFF_MASK + (size_t)BB * CC)  // 8519745

// Native vector type — __builtin_nontemporal_store rejects HIP_vector_type.
typedef float f32x4 __attribute__((ext_vector_type(4)));

// Fused kernel: 4096 blocks x 256 threads, 16 candidates/block.
//  - One candidate per 16-lane group; each lane gathers 2 independent
//    float4s (32B in flight/lane, 2x the MLP of the 32-lane version) and
//    issues 2 non-temporal stores. Segments stay 256B-coalesced.
//  - Side outputs (label/mask/loc) staged in LDS, drained by wave 0 as
//    3 coalesced segments.
//  - Blocks [0,64): additionally compute candidate_len for batch==blockIdx
//    (redundant re-read of idx/loc for 1024 candidates, noise).
//  - Block 0 thread 0 writes batch_candidate_num.
__global__ __launch_bounds__(256) void fused_kernel(
    const float* __restrict__ word_repr,
    const int*   __restrict__ anchor_cls,
    const int*   __restrict__ anchor_loc,
    const int*   __restrict__ cand_idx,
    const int*   __restrict__ cnum,
    float*       __restrict__ out)
{
    const int tid    = threadIdx.x;
    const int lane16 = tid & 15;
    const int g      = tid >> 4;                // candidate group in block, 0..15
    const int i0     = blockIdx.x * 16;
    const int i      = i0 + g;                  // candidate id, < 65536

    // side[0:16)=label, side[16:32)=mask, side[32:64)=loc (x,y interleaved)
    __shared__ float side[64];

    // Broadcast loads (uniform across the 16-lane group).
    const int b = cand_idx[3 * i + 0];
    const int w = cand_idx[3 * i + 1];
    const int a = cand_idx[3 * i + 2];
    const int base = (b * SS + w) * AA + a;      // row index into (B,S,A)

    const int2 loc = ((const int2*)anchor_loc)[base];
    const float m = (loc.x != loc.y) ? 1.0f : 0.0f;

    // Two independent 16B gathers per lane (row = 32 float4s).
    const f32x4* src = (const f32x4*)word_repr + (size_t)base * 32;
    const f32x4 v0 = src[lane16];
    const f32x4 v1 = src[lane16 + 16];

    f32x4* dst = (f32x4*)(out + OFF_REPR) + (size_t)i * 32;
    __builtin_nontemporal_store(v0 * m, dst + lane16);
    __builtin_nontemporal_store(v1 * m, dst + lane16 + 16);

    if (lane16 == 0) {
        side[g]           = (float)anchor_cls[base];
        side[16 + g]      = m;
        side[32 + 2 * g]  = (float)loc.x;
        side[33 + 2 * g]  = (float)loc.y;
    }
    __syncthreads();

    // Wave 0 drains side outputs as coalesced segments.
    if (tid < 16) {
        __builtin_nontemporal_store(side[tid], out + OFF_LABEL + i0 + tid);
    } else if (tid < 32) {
        __builtin_nontemporal_store(side[tid], out + OFF_MASK + i0 + (tid - 16));
    } else if (tid < 64) {
        __builtin_nontemporal_store(side[tid],
                                    out + OFF_LOC + 2 * (size_t)i0 + (tid - 32));
    }

    // candidate_len: first 64 blocks each reduce one batch's 1024 masks.
    if (blockIdx.x < BB) {
        const int bb = blockIdx.x;
        float msum = 0.0f;
#pragma unroll
        for (int j = 0; j < CC / 256; ++j) {
            const int c  = tid + j * 256;
            const int i2 = bb * CC + c;
            const int b2 = cand_idx[3 * i2 + 0];
            const int w2 = cand_idx[3 * i2 + 1];
            const int a2 = cand_idx[3 * i2 + 2];
            const int2 l2 = ((const int2*)anchor_loc)[(b2 * SS + w2) * AA + a2];
            msum += (l2.x != l2.y) ? 1.0f : 0.0f;
        }
#pragma unroll
        for (int off = 32; off > 0; off >>= 1)
            msum += __shfl_down(msum, off, 64);

        __shared__ float sm[4];
        if ((tid & 63) == 0) sm[tid >> 6] = msum;
        __syncthreads();
        if (tid == 0) {
            const float s = sm[0] + sm[1] + sm[2] + sm[3];
            out[OFF_LEN + bb] = fmaxf(s, 1.0f);
            if (bb == 0) out[OFF_NUM] = (float)(*cnum);
        }
    }
}

extern "C" void kernel_launch(void* const* d_in, const int* in_sizes, int n_in,
                              void* d_out, int out_size, void* d_ws, size_t ws_size,
                              hipStream_t stream) {
    const float* word_repr  = (const float*)d_in[0];
    const int*   anchor_cls = (const int*)  d_in[1];
    const int*   anchor_loc = (const int*)  d_in[2];
    const int*   cand_idx   = (const int*)  d_in[3];
    const int*   cnum       = (const int*)  d_in[4];
    float*       out        = (float*)      d_out;

    fused_kernel<<<dim3(NCAND / 16), dim3(256), 0, stream>>>(
        word_repr, anchor_cls, anchor_loc, cand_idx, cnum, out);
}